// Round 1
// baseline (486.987 us; speedup 1.0000x reference)
//
#include <hip/hip_runtime.h>

#define D_    784
#define ROWS  8
#define NCLS  10
#define BLOCK 256
#define NB    (65536 / ROWS)

// tanh-approx GELU: max |err| vs exact erf-GELU ~5e-4, within error budget.
__device__ __forceinline__ float gelu_f(float x) {
    float z = 0.7978845608028654f * fmaf(0.044715f * x, x * x, x);
    float e = __expf(2.0f * z);                      // v_exp_f32
    float t = 1.0f - 2.0f * __builtin_amdgcn_rcpf(1.0f + e);  // tanh(z)
    return 0.5f * x * (1.0f + t);
}

// Generic sparse layer for [n][r]-interleaved src/dst (K = 4 or 8).
// One ds_read_b128 serves 4 rows -> 2 reads per (n,k) for 8 rows.
template <int K>
__device__ __forceinline__ void sparse_gen(const float* __restrict__ src,
                                           float* __restrict__ dst,
                                           const int* __restrict__ idx,
                                           const float* __restrict__ w,
                                           const float* __restrict__ bias,
                                           int tid) {
    for (int n = tid; n < D_; n += BLOCK) {
        float b = bias[n];
        float aL[4] = {b, b, b, b};
        float aH[4] = {b, b, b, b};
#pragma unroll
        for (int k = 0; k < K; ++k) {
            int   j  = idx[n * K + k];
            float wk = w[n * K + k];
            float4 v0 = *(const float4*)(src + j * ROWS);
            float4 v1 = *(const float4*)(src + j * ROWS + 4);
            aL[0] = fmaf(v0.x, wk, aL[0]);
            aL[1] = fmaf(v0.y, wk, aL[1]);
            aL[2] = fmaf(v0.z, wk, aL[2]);
            aL[3] = fmaf(v0.w, wk, aL[3]);
            aH[0] = fmaf(v1.x, wk, aH[0]);
            aH[1] = fmaf(v1.y, wk, aH[1]);
            aH[2] = fmaf(v1.z, wk, aH[2]);
            aH[3] = fmaf(v1.w, wk, aH[3]);
        }
        float4* dp = (float4*)(dst + n * ROWS);
        dp[0] = make_float4(gelu_f(aL[0]), gelu_f(aL[1]), gelu_f(aL[2]), gelu_f(aL[3]));
        dp[1] = make_float4(gelu_f(aH[0]), gelu_f(aH[1]), gelu_f(aH[2]), gelu_f(aH[3]));
    }
}

__global__ __launch_bounds__(BLOCK, 3)
void circnn_kernel(const float* __restrict__ x,
                   const int* __restrict__ idx1, const float* __restrict__ w1, const float* __restrict__ b1,
                   const int* __restrict__ idx2, const float* __restrict__ w2, const float* __restrict__ b2,
                   const int* __restrict__ idx3, const float* __restrict__ w3, const float* __restrict__ b3,
                   const float* __restrict__ fcw, const float* __restrict__ fcb,
                   float* __restrict__ out) {
    __shared__ __align__(16) float bufA[ROWS * D_];   // x row-major, then h2 [n][r]
    __shared__ __align__(16) float bufB[D_ * ROWS];   // h1, then h3 [n][r]
    __shared__ float4 red4[8 * NCLS];                 // (wave*2+q) x class partials
    __shared__ float  logits[ROWS * NCLS];

    const int tid = threadIdx.x;
    const long long row0 = (long long)blockIdx.x * ROWS;

    // ---- Phase 0: stage 8 rows of x into LDS, row-major (coalesced, conflict-free)
    const float4* xv = (const float4*)(x + row0 * D_);
    float4*       av = (float4*)bufA;
    for (int v = tid; v < (ROWS * D_) / 4; v += BLOCK) av[v] = xv[v];
    __syncthreads();

    // ---- Phase 1: layer1 (K=2) from row-major x; emits [n][r] layout
    for (int n = tid; n < D_; n += BLOCK) {
        int   j0 = idx1[2 * n], j1 = idx1[2 * n + 1];
        float u0 = w1[2 * n],   u1 = w1[2 * n + 1];
        float bias = b1[n];
        float g[ROWS];
#pragma unroll
        for (int r = 0; r < ROWS; ++r) {
            float acc = fmaf(bufA[r * D_ + j0], u0, bias);
            acc       = fmaf(bufA[r * D_ + j1], u1, acc);
            g[r] = gelu_f(acc);
        }
        float4* dp = (float4*)(bufB + n * ROWS);
        dp[0] = make_float4(g[0], g[1], g[2], g[3]);
        dp[1] = make_float4(g[4], g[5], g[6], g[7]);
    }
    __syncthreads();

    // ---- Phase 2: layer2 (K=4): bufB -> bufA
    sparse_gen<4>(bufB, bufA, idx2, w2, b2, tid);
    __syncthreads();

    // ---- Phase 3: layer3 (K=8): bufA -> bufB
    sparse_gen<8>(bufA, bufB, idx3, w3, b3, tid);
    __syncthreads();

    // ---- Phase 4: FC 784->10. Thread owns (q = row-quad, n-stride); 40 accs.
    const int q = tid & 1;
    float4 acc[NCLS];
#pragma unroll
    for (int c = 0; c < NCLS; ++c) acc[c] = make_float4(0.f, 0.f, 0.f, 0.f);
    for (int n = (tid >> 1); n < D_; n += 128) {
        float4 h = *(const float4*)(bufB + n * ROWS + q * 4);
#pragma unroll
        for (int c = 0; c < NCLS; ++c) {
            float wv = fcw[c * D_ + n];
            acc[c].x = fmaf(h.x, wv, acc[c].x);
            acc[c].y = fmaf(h.y, wv, acc[c].y);
            acc[c].z = fmaf(h.z, wv, acc[c].z);
            acc[c].w = fmaf(h.w, wv, acc[c].w);
        }
    }
    // butterfly over lanes of same parity (masks 2..32): sums each q-group
#pragma unroll
    for (int m = 2; m <= 32; m <<= 1) {
#pragma unroll
        for (int c = 0; c < NCLS; ++c) {
            acc[c].x += __shfl_xor(acc[c].x, m, 64);
            acc[c].y += __shfl_xor(acc[c].y, m, 64);
            acc[c].z += __shfl_xor(acc[c].z, m, 64);
            acc[c].w += __shfl_xor(acc[c].w, m, 64);
        }
    }
    const int wave = tid >> 6;
    const int lane = tid & 63;
    if (lane < 2) {
#pragma unroll
        for (int c = 0; c < NCLS; ++c) red4[(wave * 2 + lane) * NCLS + c] = acc[c];
    }
    __syncthreads();

    // combine 4 waves' partials -> logits[r][c]
    if (tid < ROWS * NCLS) {
        int c = tid % NCLS, r = tid / NCLS;
        int qq = r >> 2, comp = r & 3;
        float s = fcb[c];
#pragma unroll
        for (int wv = 0; wv < 4; ++wv) {
            float4 v = red4[(wv * 2 + qq) * NCLS + c];
            s += (comp == 0) ? v.x : (comp == 1) ? v.y : (comp == 2) ? v.z : v.w;
        }
        logits[r * NCLS + c] = s;
    }
    __syncthreads();

    // ---- Phase 5: softmax per row, write 10 floats
    if (tid < ROWS) {
        int r = tid;
        float m = logits[r * NCLS];
#pragma unroll
        for (int c = 1; c < NCLS; ++c) m = fmaxf(m, logits[r * NCLS + c]);
        float e[NCLS];
        float s = 0.f;
#pragma unroll
        for (int c = 0; c < NCLS; ++c) {
            e[c] = __expf(logits[r * NCLS + c] - m);
            s += e[c];
        }
        float inv = 1.0f / s;
        float* op = out + (row0 + r) * NCLS;
#pragma unroll
        for (int c = 0; c < NCLS; ++c) op[c] = e[c] * inv;
    }
}

extern "C" void kernel_launch(void* const* d_in, const int* in_sizes, int n_in,
                              void* d_out, int out_size, void* d_ws, size_t ws_size,
                              hipStream_t stream) {
    const float* x    = (const float*)d_in[0];
    const int*   idx1 = (const int*)d_in[1];
    const float* w1   = (const float*)d_in[2];
    const float* b1   = (const float*)d_in[3];
    const int*   idx2 = (const int*)d_in[4];
    const float* w2   = (const float*)d_in[5];
    const float* b2   = (const float*)d_in[6];
    const int*   idx3 = (const int*)d_in[7];
    const float* w3   = (const float*)d_in[8];
    const float* b3   = (const float*)d_in[9];
    const float* fcw  = (const float*)d_in[10];
    const float* fcb  = (const float*)d_in[11];
    float* out = (float*)d_out;

    circnn_kernel<<<dim3(NB), dim3(BLOCK), 0, stream>>>(
        x, idx1, w1, b1, idx2, w2, b2, idx3, w3, b3, fcw, fcb, out);
}